// Round 11
// baseline (250.861 us; speedup 1.0000x reference)
//
#include <hip/hip_runtime.h>
#include <hip/hip_bf16.h>

#define N_NODES 100000
#define N_EDGES 1600000
#define N_AGENTS 1000

#define NB 782                 // buckets of 128 nodes (782*128 = 100096 >= 100000)
#define ABLK 512               // edge-chunk blocks for histogram/scatter
#define CHUNK (N_EDGES / ABLK) // 3125 exactly
#define CONV_BLOCKS 3125       // 800000 float4->ushort4 elements / 256

typedef short s16x8 __attribute__((ext_vector_type(8)));
typedef float f32x4 __attribute__((ext_vector_type(4)));

// float -> bf16 round-to-nearest-even
__device__ __forceinline__ unsigned short f2bf(float f) {
    unsigned u = __float_as_uint(f);
    u += 0x7fffu + ((u >> 16) & 1u);
    return (unsigned short)(u >> 16);
}
__device__ __forceinline__ float bflo(unsigned u) { return __uint_as_float(u << 16); }
__device__ __forceinline__ float bfhi(unsigned u) { return __uint_as_float(u & 0xffff0000u); }

// ---------------- A: bucket histogram (LDS atomics only) + fused prep ----------------
__global__ __launch_bounds__(256) void hist_prep_kernel(
    const int* __restrict__ dst, int* __restrict__ partialT,
    const float* __restrict__ x, unsigned short* __restrict__ xb,
    const float* __restrict__ Wl1, const float* __restrict__ Wr1,
    const float* __restrict__ Wl2, const float* __restrict__ Wr2,
    const float* __restrict__ Wl3, const float* __restrict__ Wr3,
    unsigned short* __restrict__ Wcat)
{
    int b = blockIdx.x;
    if (b < ABLK) {
        __shared__ int hist[NB];
        for (int i = threadIdx.x; i < NB; i += 256) hist[i] = 0;
        __syncthreads();
        int beg = b * CHUNK;
        for (int e = beg + threadIdx.x; e < beg + CHUNK; e += 256)
            atomicAdd(&hist[dst[e] >> 7], 1);            // LDS atomic
        __syncthreads();
        for (int i = threadIdx.x; i < NB; i += 256) partialT[i * ABLK + b] = hist[i];
    } else if (b < ABLK + CONV_BLOCKS) {
        int i = (b - ABLK) * 256 + threadIdx.x;          // exact: 800000 elements
        float4 v = ((const float4*)x)[i];
        ((ushort4*)xb)[i] = make_ushort4(f2bf(v.x), f2bf(v.y), f2bf(v.z), f2bf(v.w));
    } else {
        int gid = (b - ABLK - CONV_BLOCKS) * 256 + threadIdx.x;
        if (gid >= 3 * 2048) return;
        int L = gid >> 11, idx = gid & 2047;
        int k = idx >> 5, n = idx & 31;
        const float* Wl = (L == 0) ? Wl1 : (L == 1) ? Wl2 : Wl3;
        const float* Wr = (L == 0) ? Wr1 : (L == 1) ? Wr2 : Wr3;
        float v = (k < 32) ? Wl[k * 32 + n] : Wr[(k - 32) * 32 + n];
        Wcat[gid] = f2bf(v);
    }
}

// ---------------- B1: per-bucket prefix over ABLK chunk-partials (1 wave/bucket) ----------------
__global__ __launch_bounds__(256) void bucket_prefix_kernel(
    const int* __restrict__ partialT, int* __restrict__ baseT, int* __restrict__ tot)
{
    int wave = threadIdx.x >> 6, lane = threadIdx.x & 63;
    int t = blockIdx.x * 4 + wave;
    if (t >= NB) return;
    const int4* p = (const int4*)(partialT + (size_t)t * ABLK);
    int4 u0 = p[lane * 2], u1 = p[lane * 2 + 1];        // 8 partials per lane
    int v0 = u0.x, v1 = u0.y, v2 = u0.z, v3 = u0.w;
    int v4 = u1.x, v5 = u1.y, v6 = u1.z, v7 = u1.w;
    int p0 = 0, p1 = v0, p2 = p1 + v1, p3 = p2 + v2;
    int p4 = p3 + v3, p5 = p4 + v4, p6 = p5 + v5, p7 = p6 + v6;
    int s = p7 + v7;                                     // lane total
    int x = s;                                           // wave inclusive scan
    #pragma unroll
    for (int off = 1; off < 64; off <<= 1) {
        int y = __shfl_up(x, off);
        if (lane >= off) x += y;
    }
    int excl = x - s;                                    // exclusive prefix of lane sums
    int4* q = (int4*)(baseT + (size_t)t * ABLK);
    q[lane * 2]     = make_int4(excl + p0, excl + p1, excl + p2, excl + p3);
    q[lane * 2 + 1] = make_int4(excl + p4, excl + p5, excl + p6, excl + p7);
    if (lane == 63) tot[t] = x;
}

// ---------------- B2: exclusive scan of bucket totals -> bucket starts ----------------
__global__ __launch_bounds__(1024) void total_scan_kernel(
    const int* __restrict__ tot, int* __restrict__ bstart)
{
    __shared__ int tmp[1024];
    int t = threadIdx.x;
    int v = (t < NB) ? tot[t] : 0;
    tmp[t] = v;
    __syncthreads();
    for (int off = 1; off < 1024; off <<= 1) {
        int u = (t >= off) ? tmp[t - off] : 0;
        __syncthreads();
        tmp[t] += u;
        __syncthreads();
    }
    if (t < NB) {
        bstart[t] = tmp[t] - v;
        if (t == NB - 1) bstart[NB] = tmp[t];            // == N_EDGES
    }
}

// ---------------- C: scatter edges into buckets, packed (src | local_node<<17) ----------------
__global__ __launch_bounds__(256) void bucket_scatter_kernel(
    const int* __restrict__ src, const int* __restrict__ dst,
    const int* __restrict__ baseT, const int* __restrict__ bstart,
    int* __restrict__ ebuf)
{
    __shared__ int cur[NB];
    int b = blockIdx.x;
    for (int i = threadIdx.x; i < NB; i += 256)
        cur[i] = bstart[i] + baseT[(size_t)i * ABLK + b];
    __syncthreads();
    int beg = b * CHUNK;
    for (int e = beg + threadIdx.x; e < beg + CHUNK; e += 256) {
        int d = dst[e];
        int slot = atomicAdd(&cur[d >> 7], 1);           // LDS atomic
        ebuf[slot] = src[e] | ((d & 127) << 17);         // src < 2^17
    }
}

// ---------------- D: per-bucket CSR finalize + per-block degree histogram ----------------
__global__ __launch_bounds__(256) void bucket_csr_kernel(
    const int* __restrict__ bstart, const int* __restrict__ ebuf,
    int* __restrict__ rowptr, float* __restrict__ inv, int* __restrict__ esrc,
    int* __restrict__ dbinP)
{
    __shared__ int hist[128], cur[128], tmp[256], dhist[64];
    int b = blockIdx.x;
    int t = threadIdx.x;
    int beg = bstart[b], end = bstart[b + 1];
    if (t < 128) hist[t] = 0;
    if (t < 64) dhist[t] = 0;
    __syncthreads();
    for (int i = beg + t; i < end; i += 256)
        atomicAdd(&hist[(ebuf[i] >> 17) & 127], 1);      // LDS atomic
    __syncthreads();
    int v = (t < 128) ? hist[t] : 0;
    tmp[t] = v;
    __syncthreads();
    for (int off = 1; off < 256; off <<= 1) {
        int u = (t >= off) ? tmp[t - off] : 0;
        __syncthreads();
        tmp[t] += u;
        __syncthreads();
    }
    int excl = tmp[t] - v;                               // exclusive within bucket
    int node = b * 128 + t;
    if (t < 128 && node < N_NODES) {
        rowptr[node] = beg + excl;
        inv[node] = 1.0f / fmaxf((float)v, 1.0f);
        cur[t] = beg + excl;
        atomicAdd(&dhist[min(v, 63)], 1);                // degree-class histogram
    }
    if (b == NB - 1 && t == 0) rowptr[N_NODES] = N_EDGES;
    __syncthreads();
    if (t < 64) dbinP[b * 64 + t] = dhist[t];
    for (int i = beg + t; i < end; i += 256) {
        int p = ebuf[i];
        int slot = atomicAdd(&cur[(p >> 17) & 127], 1);  // LDS atomic
        esrc[slot] = p & 0x1FFFF;                        // within-bucket 8KB region
    }
}

// ---------------- E1: per-degree-bin prefix over NB block partials ----------------
// wave = bin; lane owns contiguous b-range [lane*13, lane*13+13)
__global__ __launch_bounds__(256) void deg_scan_kernel(
    const int* __restrict__ dbinP, int* __restrict__ dbaseP, int* __restrict__ dtot)
{
    int wave = threadIdx.x >> 6, lane = threadIdx.x & 63;
    int bin = blockIdx.x * 4 + wave;                     // grid 16 -> bins 0..63
    int vals[13];
    int s = 0;
    #pragma unroll
    for (int it = 0; it < 13; it++) {
        int b = lane * 13 + it;
        int v = (b < NB) ? dbinP[b * 64 + bin] : 0;
        vals[it] = v; s += v;
    }
    int x = s;
    #pragma unroll
    for (int off = 1; off < 64; off <<= 1) {
        int y = __shfl_up(x, off);
        if (lane >= off) x += y;
    }
    int run = x - s;                                     // exclusive prefix of lane sums
    #pragma unroll
    for (int it = 0; it < 13; it++) {
        int b = lane * 13 + it;
        if (b < NB) dbaseP[b * 64 + bin] = run;
        run += vals[it];
    }
    if (lane == 63) dtot[bin] = x;
}

// ---------------- E2: place nodes into degree-sorted perm (heavy bins first) ----------------
__global__ __launch_bounds__(256) void perm_place_kernel(
    const int* __restrict__ rowptr, const int* __restrict__ dbinP,
    const int* __restrict__ dbaseP, const int* __restrict__ dtot,
    int* __restrict__ perm)
{
    __shared__ int lhist[2][64];
    __shared__ int sstart[64];
    int t = threadIdx.x;
    if (t < 64) { lhist[0][t] = 0; lhist[1][t] = 0; }
    if (t < 64) {                                        // descending bin starts
        int s = 0;
        for (int j = t + 1; j < 64; j++) s += dtot[j];
        sstart[t] = s;
    }
    __syncthreads();
    int i = blockIdx.x * 256 + t;
    if (i >= N_NODES) return;
    int deg = rowptr[i + 1] - rowptr[i];
    int bin = min(deg, 63);
    int half = t >> 7;
    int rank = atomicAdd(&lhist[half][bin], 1);
    int csrb = i >> 7;
    int pos = sstart[bin] + dbaseP[csrb * 64 + bin] + rank;
    perm[pos] = i;
}

// ---------------- fused layer: aggregate (regs) -> LDS -> MFMA dense -> out ----------------
// Tiles iterate perm[] (degree-sorted) so a block's 64 nodes have ~equal degree
// and the pre-MFMA barrier waits ~mean instead of ~max degree.
__global__ __launch_bounds__(256) void sage_fused_kernel(
    const int* __restrict__ rowptr, const int* __restrict__ esrc,
    const float* __restrict__ inv, const unsigned short* __restrict__ hb,
    const unsigned short* __restrict__ Wcat, const float* __restrict__ bl,
    const float* __restrict__ Wout, const float* __restrict__ bout,
    const int* __restrict__ perm, int use_perm,
    void* __restrict__ outp, int n_nodes, int final)
{
    __shared__ unsigned short sW[2048];      // 64k x 32n bf16 layer weights
    __shared__ float sb[32];
    __shared__ unsigned short smean[64 * 40];
    __shared__ float sh3[64 * 33];
    __shared__ float sWo[256];
    __shared__ float sbo[8];

    int tid = threadIdx.x;
    ((uint4*)sW)[tid] = ((const uint4*)Wcat)[tid];       // 256 x 16B = 4KB exact
    if (tid < 32) sb[tid] = bl[tid];
    if (final) {
        sWo[tid] = Wout[tid];                            // 256 exact
        if (tid < 8) sbo[tid] = bout[tid];
    }

    int lane = tid & 63, wave = tid >> 6;

    // ---- phase 1: aggregate ----
    int g = lane >> 2, q = lane & 3;
    int idxA = blockIdx.x * 64 + wave * 16 + g;
    int nodeA = -1;
    if (idxA < n_nodes) nodeA = use_perm ? perm[idxA] : idxA;
    int beg = 0, end = 0;
    if (nodeA >= 0) { beg = rowptr[nodeA]; end = rowptr[nodeA + 1]; }
    float a0 = 0.f, a1 = 0.f, a2 = 0.f, a3 = 0.f;
    float a4 = 0.f, a5 = 0.f, a6 = 0.f, a7 = 0.f;
    int j = beg;
    for (; j + 1 < end; j += 2) {
        int s0 = esrc[j];
        int s1 = esrc[j + 1];
        uint4 u0 = *(const uint4*)(hb + s0 * 32 + q * 8);
        uint4 u1 = *(const uint4*)(hb + s1 * 32 + q * 8);
        a0 += bflo(u0.x); a1 += bfhi(u0.x);
        a2 += bflo(u0.y); a3 += bfhi(u0.y);
        a4 += bflo(u0.z); a5 += bfhi(u0.z);
        a6 += bflo(u0.w); a7 += bfhi(u0.w);
        a0 += bflo(u1.x); a1 += bfhi(u1.x);
        a2 += bflo(u1.y); a3 += bfhi(u1.y);
        a4 += bflo(u1.z); a5 += bfhi(u1.z);
        a6 += bflo(u1.w); a7 += bfhi(u1.w);
    }
    if (j < end) {
        int s = esrc[j];
        uint4 u = *(const uint4*)(hb + s * 32 + q * 8);
        a0 += bflo(u.x); a1 += bfhi(u.x);
        a2 += bflo(u.y); a3 += bfhi(u.y);
        a4 += bflo(u.z); a5 += bfhi(u.z);
        a6 += bflo(u.w); a7 += bfhi(u.w);
    }
    float iv = (nodeA >= 0) ? inv[nodeA] : 0.f;
    uint4 o;
    o.x = (unsigned)f2bf(a0 * iv) | ((unsigned)f2bf(a1 * iv) << 16);
    o.y = (unsigned)f2bf(a2 * iv) | ((unsigned)f2bf(a3 * iv) << 16);
    o.z = (unsigned)f2bf(a4 * iv) | ((unsigned)f2bf(a5 * iv) << 16);
    o.w = (unsigned)f2bf(a6 * iv) | ((unsigned)f2bf(a7 * iv) << 16);
    int mrow = wave * 16 + g;
    *(uint4*)&smean[mrow * 40 + q * 8] = o;
    __syncthreads();

    // ---- phase 2: dense via MFMA ----
    int l15 = lane & 15, quad = lane >> 4;
    s16x8 bf_[2][2];
    #pragma unroll
    for (int kt = 0; kt < 2; kt++)
        #pragma unroll
        for (int nt = 0; nt < 2; nt++)
            #pragma unroll
            for (int jj = 0; jj < 8; jj++) {
                int k = kt * 32 + quad * 8 + jj;
                bf_[kt][nt][jj] = (short)sW[k * 32 + l15 + nt * 16];
            }
    float bias0 = sb[l15], bias1 = sb[l15 + 16];

    int tilebase = blockIdx.x * 64 + wave * 16;
    int idxD = tilebase + l15;
    int pnode = 0;
    if (idxD < n_nodes) pnode = use_perm ? perm[idxD] : idxD;
    s16x8 am = *(const s16x8*)&smean[(wave * 16 + l15) * 40 + quad * 8];
    s16x8 as = *(const s16x8*)(hb + (size_t)pnode * 32 + quad * 8);
    f32x4 acc0 = {0.f, 0.f, 0.f, 0.f};
    f32x4 acc1 = {0.f, 0.f, 0.f, 0.f};
    acc0 = __builtin_amdgcn_mfma_f32_16x16x32_bf16(am, bf_[0][0], acc0, 0, 0, 0);
    acc0 = __builtin_amdgcn_mfma_f32_16x16x32_bf16(as, bf_[1][0], acc0, 0, 0, 0);
    acc1 = __builtin_amdgcn_mfma_f32_16x16x32_bf16(am, bf_[0][1], acc1, 0, 0, 0);
    acc1 = __builtin_amdgcn_mfma_f32_16x16x32_bf16(as, bf_[1][1], acc1, 0, 0, 0);

    if (!final) {
        #pragma unroll
        for (int r = 0; r < 4; r++) {
            int oidx = tilebase + quad * 4 + r;
            if (oidx < n_nodes) {
                int onode = __shfl(pnode, quad * 4 + r);   // lanes 0..15 hold tile nodes
                ((unsigned short*)outp)[onode * 32 + l15]      = f2bf(fmaxf(acc0[r] + bias0, 0.f));
                ((unsigned short*)outp)[onode * 32 + l15 + 16] = f2bf(fmaxf(acc1[r] + bias1, 0.f));
            }
        }
    } else {
        #pragma unroll
        for (int r = 0; r < 4; r++) {
            int row = wave * 16 + quad * 4 + r;
            sh3[row * 33 + l15]      = fmaxf(acc0[r] + bias0, 0.f);
            sh3[row * 33 + l15 + 16] = fmaxf(acc1[r] + bias1, 0.f);
        }
        __syncthreads();
        // 64 nodes x 8 out-channels = 512 outputs, 2 per thread
        #pragma unroll
        for (int i = tid; i < 512; i += 256) {
            int ln = i >> 3, c = i & 7;
            int gn = blockIdx.x * 64 + ln;
            if (gn < N_AGENTS) {
                float ov = sbo[c];
                #pragma unroll
                for (int k = 0; k < 32; k++) ov += sh3[ln * 33 + k] * sWo[k * 8 + c];
                ((float*)outp)[gn * 8 + c] = ov;
            }
        }
    }
}

extern "C" void kernel_launch(void* const* d_in, const int* in_sizes, int n_in,
                              void* d_out, int out_size, void* d_ws, size_t ws_size,
                              hipStream_t stream) {
    const float* x   = (const float*)d_in[0];
    const int* ei    = (const int*)d_in[1];
    const float* Wl1 = (const float*)d_in[2];
    const float* bl1 = (const float*)d_in[3];
    const float* Wr1 = (const float*)d_in[4];
    const float* Wl2 = (const float*)d_in[5];
    const float* bl2 = (const float*)d_in[6];
    const float* Wr2 = (const float*)d_in[7];
    const float* Wl3 = (const float*)d_in[8];
    const float* bl3 = (const float*)d_in[9];
    const float* Wr3 = (const float*)d_in[10];
    const float* Wout = (const float*)d_in[11];
    const float* bout = (const float*)d_in[12];
    float* out = (float*)d_out;

    const int* src = ei;
    const int* dst = ei + N_EDGES;

    // workspace layout (ebuf aliases hAb: ebuf dead after bucket_csr_kernel,
    // hAb first written by fused layer 1)
    char* ws = (char*)d_ws;
    int*   rowptr   = (int*)ws;                                ws += (size_t)(N_NODES + 8) * 4;
    float* inv      = (float*)ws;                              ws += (size_t)N_NODES * 4;
    int*   partialT = (int*)ws;                                ws += (size_t)NB * ABLK * 4;
    int*   baseT    = (int*)ws;                                ws += (size_t)NB * ABLK * 4;
    int*   tot      = (int*)ws;                                ws += 784 * 4;
    int*   bstart   = (int*)ws;                                ws += 784 * 4;
    int*   esrc     = (int*)ws;                                ws += (size_t)N_EDGES * 4;
    unsigned short* hXb   = (unsigned short*)ws;               ws += (size_t)N_NODES * 32 * 2;
    unsigned short* hAb   = (unsigned short*)ws;               ws += (size_t)N_NODES * 32 * 2;
    unsigned short* hBb   = (unsigned short*)ws;               ws += (size_t)N_NODES * 32 * 2;
    unsigned short* Wcat  = (unsigned short*)ws;               ws += 3 * 2048 * 2;
    int*   dbinP    = (int*)ws;                                ws += (size_t)NB * 64 * 4;
    int*   dbaseP   = (int*)ws;                                ws += (size_t)NB * 64 * 4;
    int*   dtot     = (int*)ws;                                ws += 64 * 4;
    int*   perm     = (int*)ws;                                ws += (size_t)N_NODES * 4;
    int*   ebuf     = (int*)hAb;    // alias

    // ---- CSR build (no global atomics) + fused prep ----
    hist_prep_kernel<<<ABLK + CONV_BLOCKS + 24, 256, 0, stream>>>(
        dst, partialT, x, hXb, Wl1, Wr1, Wl2, Wr2, Wl3, Wr3, Wcat);
    bucket_prefix_kernel<<<(NB + 3) / 4, 256, 0, stream>>>(partialT, baseT, tot);
    total_scan_kernel<<<1, 1024, 0, stream>>>(tot, bstart);
    bucket_scatter_kernel<<<ABLK, 256, 0, stream>>>(src, dst, baseT, bstart, ebuf);
    bucket_csr_kernel<<<NB, 256, 0, stream>>>(bstart, ebuf, rowptr, inv, esrc, dbinP);

    // ---- degree-sorted permutation (for load-balanced tiles) ----
    deg_scan_kernel<<<16, 256, 0, stream>>>(dbinP, dbaseP, dtot);
    perm_place_kernel<<<(N_NODES + 255) / 256, 256, 0, stream>>>(rowptr, dbinP, dbaseP, dtot, perm);

    // ---- fused layers ----
    sage_fused_kernel<<<(N_NODES + 63) / 64, 256, 0, stream>>>(
        rowptr, esrc, inv, hXb, Wcat, bl1, Wout, bout, perm, 1, hAb, N_NODES, 0);
    sage_fused_kernel<<<(N_NODES + 63) / 64, 256, 0, stream>>>(
        rowptr, esrc, inv, hAb, Wcat + 2048, bl2, Wout, bout, perm, 1, hBb, N_NODES, 0);
    sage_fused_kernel<<<(N_AGENTS + 63) / 64, 256, 0, stream>>>(
        rowptr, esrc, inv, hBb, Wcat + 4096, bl3, Wout, bout, perm, 0, out, N_AGENTS, 1);
}

// Round 12
// 203.595 us; speedup vs baseline: 1.2322x; 1.2322x over previous
//
#include <hip/hip_runtime.h>
#include <hip/hip_bf16.h>

#define N_NODES 100000
#define N_EDGES 1600000
#define N_AGENTS 1000

#define NB 782                 // buckets of 128 nodes (782*128 = 100096 >= 100000)
#define ABLK 512               // edge-chunk blocks for histogram/scatter
#define CHUNK (N_EDGES / ABLK) // 3125 exactly
#define CONV_BLOCKS 3125       // 800000 float4->ushort4 elements / 256

typedef short s16x8 __attribute__((ext_vector_type(8)));
typedef float f32x4 __attribute__((ext_vector_type(4)));

// float -> bf16 round-to-nearest-even
__device__ __forceinline__ unsigned short f2bf(float f) {
    unsigned u = __float_as_uint(f);
    u += 0x7fffu + ((u >> 16) & 1u);
    return (unsigned short)(u >> 16);
}
__device__ __forceinline__ float bflo(unsigned u) { return __uint_as_float(u << 16); }
__device__ __forceinline__ float bfhi(unsigned u) { return __uint_as_float(u & 0xffff0000u); }

// ---------------- A: bucket histogram (LDS atomics only) + fused prep ----------------
__global__ __launch_bounds__(256) void hist_prep_kernel(
    const int* __restrict__ dst, int* __restrict__ partialT,
    const float* __restrict__ x, unsigned short* __restrict__ xb,
    const float* __restrict__ Wl1, const float* __restrict__ Wr1,
    const float* __restrict__ Wl2, const float* __restrict__ Wr2,
    const float* __restrict__ Wl3, const float* __restrict__ Wr3,
    unsigned short* __restrict__ Wcat)
{
    int b = blockIdx.x;
    if (b < ABLK) {
        __shared__ int hist[NB];
        for (int i = threadIdx.x; i < NB; i += 256) hist[i] = 0;
        __syncthreads();
        int beg = b * CHUNK;
        for (int e = beg + threadIdx.x; e < beg + CHUNK; e += 256)
            atomicAdd(&hist[dst[e] >> 7], 1);            // LDS atomic
        __syncthreads();
        for (int i = threadIdx.x; i < NB; i += 256) partialT[i * ABLK + b] = hist[i];
    } else if (b < ABLK + CONV_BLOCKS) {
        int i = (b - ABLK) * 256 + threadIdx.x;          // exact: 800000 elements
        float4 v = ((const float4*)x)[i];
        ((ushort4*)xb)[i] = make_ushort4(f2bf(v.x), f2bf(v.y), f2bf(v.z), f2bf(v.w));
    } else {
        int gid = (b - ABLK - CONV_BLOCKS) * 256 + threadIdx.x;
        if (gid >= 3 * 2048) return;
        int L = gid >> 11, idx = gid & 2047;
        int k = idx >> 5, n = idx & 31;
        const float* Wl = (L == 0) ? Wl1 : (L == 1) ? Wl2 : Wl3;
        const float* Wr = (L == 0) ? Wr1 : (L == 1) ? Wr2 : Wr3;
        float v = (k < 32) ? Wl[k * 32 + n] : Wr[(k - 32) * 32 + n];
        Wcat[gid] = f2bf(v);
    }
}

// ---------------- B1: per-bucket prefix over ABLK chunk-partials (1 wave/bucket) ----------------
__global__ __launch_bounds__(256) void bucket_prefix_kernel(
    const int* __restrict__ partialT, int* __restrict__ baseT, int* __restrict__ tot)
{
    int wave = threadIdx.x >> 6, lane = threadIdx.x & 63;
    int t = blockIdx.x * 4 + wave;
    if (t >= NB) return;
    const int4* p = (const int4*)(partialT + (size_t)t * ABLK);
    int4 u0 = p[lane * 2], u1 = p[lane * 2 + 1];        // 8 partials per lane
    int v0 = u0.x, v1 = u0.y, v2 = u0.z, v3 = u0.w;
    int v4 = u1.x, v5 = u1.y, v6 = u1.z, v7 = u1.w;
    int p0 = 0, p1 = v0, p2 = p1 + v1, p3 = p2 + v2;
    int p4 = p3 + v3, p5 = p4 + v4, p6 = p5 + v5, p7 = p6 + v6;
    int s = p7 + v7;                                     // lane total
    int x = s;                                           // wave inclusive scan
    #pragma unroll
    for (int off = 1; off < 64; off <<= 1) {
        int y = __shfl_up(x, off);
        if (lane >= off) x += y;
    }
    int excl = x - s;                                    // exclusive prefix of lane sums
    int4* q = (int4*)(baseT + (size_t)t * ABLK);
    q[lane * 2]     = make_int4(excl + p0, excl + p1, excl + p2, excl + p3);
    q[lane * 2 + 1] = make_int4(excl + p4, excl + p5, excl + p6, excl + p7);
    if (lane == 63) tot[t] = x;
}

// ---------------- B2: exclusive scan of bucket totals -> bucket starts ----------------
__global__ __launch_bounds__(1024) void total_scan_kernel(
    const int* __restrict__ tot, int* __restrict__ bstart)
{
    __shared__ int tmp[1024];
    int t = threadIdx.x;
    int v = (t < NB) ? tot[t] : 0;
    tmp[t] = v;
    __syncthreads();
    for (int off = 1; off < 1024; off <<= 1) {
        int u = (t >= off) ? tmp[t - off] : 0;
        __syncthreads();
        tmp[t] += u;
        __syncthreads();
    }
    if (t < NB) {
        bstart[t] = tmp[t] - v;
        if (t == NB - 1) bstart[NB] = tmp[t];            // == N_EDGES
    }
}

// ---------------- C: scatter edges into buckets, packed (src | local_node<<17) ----------------
__global__ __launch_bounds__(256) void bucket_scatter_kernel(
    const int* __restrict__ src, const int* __restrict__ dst,
    const int* __restrict__ baseT, const int* __restrict__ bstart,
    int* __restrict__ ebuf)
{
    __shared__ int cur[NB];
    int b = blockIdx.x;
    for (int i = threadIdx.x; i < NB; i += 256)
        cur[i] = bstart[i] + baseT[(size_t)i * ABLK + b];
    __syncthreads();
    int beg = b * CHUNK;
    for (int e = beg + threadIdx.x; e < beg + CHUNK; e += 256) {
        int d = dst[e];
        int slot = atomicAdd(&cur[d >> 7], 1);           // LDS atomic
        ebuf[slot] = src[e] | ((d & 127) << 17);         // src < 2^17
    }
}

// ---------------- D: per-bucket CSR finalize: rowptr, inv, src-partitioned esrc ----------------
// Each node's neighbor list is partitioned: src < N_NODES/2 at the front,
// src >= N_NODES/2 at the back (dual cursors). The aggregate loop then walks
// low-src edges first device-wide -> working set halves (3.2MB fits 4MB L2).
__global__ __launch_bounds__(256) void bucket_csr_kernel(
    const int* __restrict__ bstart, const int* __restrict__ ebuf,
    int* __restrict__ rowptr, float* __restrict__ inv, int* __restrict__ esrc)
{
    __shared__ int hist[128], cur[128], curh[128], tmp[256];
    int b = blockIdx.x;
    int t = threadIdx.x;
    int beg = bstart[b], end = bstart[b + 1];
    if (t < 128) hist[t] = 0;
    __syncthreads();
    for (int i = beg + t; i < end; i += 256)
        atomicAdd(&hist[(ebuf[i] >> 17) & 127], 1);      // LDS atomic
    __syncthreads();
    int v = (t < 128) ? hist[t] : 0;
    tmp[t] = v;
    __syncthreads();
    for (int off = 1; off < 256; off <<= 1) {
        int u = (t >= off) ? tmp[t - off] : 0;
        __syncthreads();
        tmp[t] += u;
        __syncthreads();
    }
    int excl = tmp[t] - v;                               // exclusive within bucket
    int node = b * 128 + t;
    if (t < 128 && node < N_NODES) {
        rowptr[node] = beg + excl;
        inv[node] = 1.0f / fmaxf((float)v, 1.0f);
        cur[t]  = beg + excl;                            // low-src cursor (front)
        curh[t] = beg + excl + v;                        // high-src cursor (back)
    }
    if (b == NB - 1 && t == 0) rowptr[N_NODES] = N_EDGES;
    __syncthreads();
    for (int i = beg + t; i < end; i += 256) {
        int p = ebuf[i];
        int ln = (p >> 17) & 127;
        int s = p & 0x1FFFF;
        int slot = (s < N_NODES / 2) ? atomicAdd(&cur[ln], 1)
                                     : atomicSub(&curh[ln], 1) - 1;
        esrc[slot] = s;
    }
}

// ---------------- fused layer: aggregate (regs) -> LDS -> MFMA dense -> out ----------------
// Block = 64 nodes. Phase 1: 4 lanes/node, lane owns 8 channels, fp32 acc over
// all neighbors (low-src first -> L2-friendly); pack bf16 mean into LDS
// (stride 40 shorts: 16B-aligned, 2-way bank aliasing = free). Phase 2: wave w
// MFMAs nodes [w*16, w*16+16); weights staged in LDS.
// final=1: layer-3 + 32->8 output projection through a second LDS stage.
__global__ __launch_bounds__(256) void sage_fused_kernel(
    const int* __restrict__ rowptr, const int* __restrict__ esrc,
    const float* __restrict__ inv, const unsigned short* __restrict__ hb,
    const unsigned short* __restrict__ Wcat, const float* __restrict__ bl,
    const float* __restrict__ Wout, const float* __restrict__ bout,
    void* __restrict__ outp, int n_nodes, int final)
{
    __shared__ unsigned short sW[2048];      // 64k x 32n bf16 layer weights
    __shared__ float sb[32];
    __shared__ unsigned short smean[64 * 40];
    __shared__ float sh3[64 * 33];
    __shared__ float sWo[256];
    __shared__ float sbo[8];

    int tid = threadIdx.x;
    ((uint4*)sW)[tid] = ((const uint4*)Wcat)[tid];       // 256 x 16B = 4KB exact
    if (tid < 32) sb[tid] = bl[tid];
    if (final) {
        sWo[tid] = Wout[tid];                            // 256 exact
        if (tid < 8) sbo[tid] = bout[tid];
    }

    int lane = tid & 63, wave = tid >> 6;

    // ---- phase 1: aggregate ----
    int g = lane >> 2, q = lane & 3;
    int nodeA = blockIdx.x * 64 + wave * 16 + g;
    int beg = 0, end = 0;
    if (nodeA < n_nodes) { beg = rowptr[nodeA]; end = rowptr[nodeA + 1]; }
    float a0 = 0.f, a1 = 0.f, a2 = 0.f, a3 = 0.f;
    float a4 = 0.f, a5 = 0.f, a6 = 0.f, a7 = 0.f;
    int j = beg;
    for (; j + 1 < end; j += 2) {
        int s0 = esrc[j];
        int s1 = esrc[j + 1];
        uint4 u0 = *(const uint4*)(hb + s0 * 32 + q * 8);
        uint4 u1 = *(const uint4*)(hb + s1 * 32 + q * 8);
        a0 += bflo(u0.x); a1 += bfhi(u0.x);
        a2 += bflo(u0.y); a3 += bfhi(u0.y);
        a4 += bflo(u0.z); a5 += bfhi(u0.z);
        a6 += bflo(u0.w); a7 += bfhi(u0.w);
        a0 += bflo(u1.x); a1 += bfhi(u1.x);
        a2 += bflo(u1.y); a3 += bfhi(u1.y);
        a4 += bflo(u1.z); a5 += bfhi(u1.z);
        a6 += bflo(u1.w); a7 += bfhi(u1.w);
    }
    if (j < end) {
        int s = esrc[j];
        uint4 u = *(const uint4*)(hb + s * 32 + q * 8);
        a0 += bflo(u.x); a1 += bfhi(u.x);
        a2 += bflo(u.y); a3 += bfhi(u.y);
        a4 += bflo(u.z); a5 += bfhi(u.z);
        a6 += bflo(u.w); a7 += bfhi(u.w);
    }
    float iv = (nodeA < n_nodes) ? inv[nodeA] : 0.f;
    uint4 o;
    o.x = (unsigned)f2bf(a0 * iv) | ((unsigned)f2bf(a1 * iv) << 16);
    o.y = (unsigned)f2bf(a2 * iv) | ((unsigned)f2bf(a3 * iv) << 16);
    o.z = (unsigned)f2bf(a4 * iv) | ((unsigned)f2bf(a5 * iv) << 16);
    o.w = (unsigned)f2bf(a6 * iv) | ((unsigned)f2bf(a7 * iv) << 16);
    int mrow = wave * 16 + g;
    *(uint4*)&smean[mrow * 40 + q * 8] = o;
    __syncthreads();

    // ---- phase 2: dense via MFMA ----
    int l15 = lane & 15, quad = lane >> 4;
    s16x8 bf_[2][2];
    #pragma unroll
    for (int kt = 0; kt < 2; kt++)
        #pragma unroll
        for (int nt = 0; nt < 2; nt++)
            #pragma unroll
            for (int jj = 0; jj < 8; jj++) {
                int k = kt * 32 + quad * 8 + jj;
                bf_[kt][nt][jj] = (short)sW[k * 32 + l15 + nt * 16];
            }
    float bias0 = sb[l15], bias1 = sb[l15 + 16];

    int tilebase = blockIdx.x * 64 + wave * 16;
    int nodeD = tilebase + l15;
    int na = min(nodeD, n_nodes - 1);
    s16x8 am = *(const s16x8*)&smean[(wave * 16 + l15) * 40 + quad * 8];
    s16x8 as = *(const s16x8*)(hb + (size_t)na * 32 + quad * 8);
    f32x4 acc0 = {0.f, 0.f, 0.f, 0.f};
    f32x4 acc1 = {0.f, 0.f, 0.f, 0.f};
    acc0 = __builtin_amdgcn_mfma_f32_16x16x32_bf16(am, bf_[0][0], acc0, 0, 0, 0);
    acc0 = __builtin_amdgcn_mfma_f32_16x16x32_bf16(as, bf_[1][0], acc0, 0, 0, 0);
    acc1 = __builtin_amdgcn_mfma_f32_16x16x32_bf16(am, bf_[0][1], acc1, 0, 0, 0);
    acc1 = __builtin_amdgcn_mfma_f32_16x16x32_bf16(as, bf_[1][1], acc1, 0, 0, 0);

    if (!final) {
        #pragma unroll
        for (int r = 0; r < 4; r++) {
            int onode = tilebase + quad * 4 + r;
            if (onode < n_nodes) {
                ((unsigned short*)outp)[onode * 32 + l15]      = f2bf(fmaxf(acc0[r] + bias0, 0.f));
                ((unsigned short*)outp)[onode * 32 + l15 + 16] = f2bf(fmaxf(acc1[r] + bias1, 0.f));
            }
        }
    } else {
        #pragma unroll
        for (int r = 0; r < 4; r++) {
            int row = wave * 16 + quad * 4 + r;
            sh3[row * 33 + l15]      = fmaxf(acc0[r] + bias0, 0.f);
            sh3[row * 33 + l15 + 16] = fmaxf(acc1[r] + bias1, 0.f);
        }
        __syncthreads();
        // 64 nodes x 8 out-channels = 512 outputs, 2 per thread
        #pragma unroll
        for (int i = tid; i < 512; i += 256) {
            int ln = i >> 3, c = i & 7;
            int gn = blockIdx.x * 64 + ln;
            if (gn < N_AGENTS) {
                float ov = sbo[c];
                #pragma unroll
                for (int k = 0; k < 32; k++) ov += sh3[ln * 33 + k] * sWo[k * 8 + c];
                ((float*)outp)[gn * 8 + c] = ov;
            }
        }
    }
}

extern "C" void kernel_launch(void* const* d_in, const int* in_sizes, int n_in,
                              void* d_out, int out_size, void* d_ws, size_t ws_size,
                              hipStream_t stream) {
    const float* x   = (const float*)d_in[0];
    const int* ei    = (const int*)d_in[1];
    const float* Wl1 = (const float*)d_in[2];
    const float* bl1 = (const float*)d_in[3];
    const float* Wr1 = (const float*)d_in[4];
    const float* Wl2 = (const float*)d_in[5];
    const float* bl2 = (const float*)d_in[6];
    const float* Wr2 = (const float*)d_in[7];
    const float* Wl3 = (const float*)d_in[8];
    const float* bl3 = (const float*)d_in[9];
    const float* Wr3 = (const float*)d_in[10];
    const float* Wout = (const float*)d_in[11];
    const float* bout = (const float*)d_in[12];
    float* out = (float*)d_out;

    const int* src = ei;
    const int* dst = ei + N_EDGES;

    // workspace layout (ebuf aliases hAb: ebuf dead after bucket_csr_kernel,
    // hAb first written by fused layer 1)
    char* ws = (char*)d_ws;
    int*   rowptr   = (int*)ws;                                ws += (size_t)(N_NODES + 8) * 4;
    float* inv      = (float*)ws;                              ws += (size_t)N_NODES * 4;
    int*   partialT = (int*)ws;                                ws += (size_t)NB * ABLK * 4;
    int*   baseT    = (int*)ws;                                ws += (size_t)NB * ABLK * 4;
    int*   tot      = (int*)ws;                                ws += 784 * 4;
    int*   bstart   = (int*)ws;                                ws += 784 * 4;
    int*   esrc     = (int*)ws;                                ws += (size_t)N_EDGES * 4;
    unsigned short* hXb   = (unsigned short*)ws;               ws += (size_t)N_NODES * 32 * 2;
    unsigned short* hAb   = (unsigned short*)ws;               ws += (size_t)N_NODES * 32 * 2;
    unsigned short* hBb   = (unsigned short*)ws;               ws += (size_t)N_NODES * 32 * 2;
    unsigned short* Wcat  = (unsigned short*)ws;               ws += 3 * 2048 * 2;
    int*   ebuf     = (int*)hAb;    // alias

    // ---- CSR build (no global atomics) + fused prep ----
    hist_prep_kernel<<<ABLK + CONV_BLOCKS + 24, 256, 0, stream>>>(
        dst, partialT, x, hXb, Wl1, Wr1, Wl2, Wr2, Wl3, Wr3, Wcat);
    bucket_prefix_kernel<<<(NB + 3) / 4, 256, 0, stream>>>(partialT, baseT, tot);
    total_scan_kernel<<<1, 1024, 0, stream>>>(tot, bstart);
    bucket_scatter_kernel<<<ABLK, 256, 0, stream>>>(src, dst, baseT, bstart, ebuf);
    bucket_csr_kernel<<<NB, 256, 0, stream>>>(bstart, ebuf, rowptr, inv, esrc);

    // ---- fused layers ----
    sage_fused_kernel<<<(N_NODES + 63) / 64, 256, 0, stream>>>(
        rowptr, esrc, inv, hXb, Wcat, bl1, Wout, bout, hAb, N_NODES, 0);
    sage_fused_kernel<<<(N_NODES + 63) / 64, 256, 0, stream>>>(
        rowptr, esrc, inv, hAb, Wcat + 2048, bl2, Wout, bout, hBb, N_NODES, 0);
    sage_fused_kernel<<<(N_AGENTS + 63) / 64, 256, 0, stream>>>(
        rowptr, esrc, inv, hBb, Wcat + 4096, bl3, Wout, bout, out, N_AGENTS, 1);
}

// Round 13
// 196.196 us; speedup vs baseline: 1.2786x; 1.0377x over previous
//
#include <hip/hip_runtime.h>
#include <hip/hip_bf16.h>

#define N_NODES 100000
#define N_EDGES 1600000
#define N_AGENTS 1000

#define NB 782                 // buckets of 128 nodes (782*128 = 100096 >= 100000)
#define ABLK 512               // edge-chunk blocks for histogram/scatter
#define CHUNK (N_EDGES / ABLK) // 3125 exactly
#define CONV_BLOCKS 3125       // 800000 float4->ushort4 elements / 256

typedef short s16x8 __attribute__((ext_vector_type(8)));
typedef float f32x4 __attribute__((ext_vector_type(4)));

// float -> bf16 round-to-nearest-even
__device__ __forceinline__ unsigned short f2bf(float f) {
    unsigned u = __float_as_uint(f);
    u += 0x7fffu + ((u >> 16) & 1u);
    return (unsigned short)(u >> 16);
}
__device__ __forceinline__ float bflo(unsigned u) { return __uint_as_float(u << 16); }
__device__ __forceinline__ float bfhi(unsigned u) { return __uint_as_float(u & 0xffff0000u); }

// ---------------- A: bucket histogram (LDS atomics only) + fused prep ----------------
__global__ __launch_bounds__(256) void hist_prep_kernel(
    const int* __restrict__ dst, int* __restrict__ partialT,
    const float* __restrict__ x, unsigned short* __restrict__ xb,
    const float* __restrict__ Wl1, const float* __restrict__ Wr1,
    const float* __restrict__ Wl2, const float* __restrict__ Wr2,
    const float* __restrict__ Wl3, const float* __restrict__ Wr3,
    unsigned short* __restrict__ Wcat)
{
    int b = blockIdx.x;
    if (b < ABLK) {
        __shared__ int hist[NB];
        for (int i = threadIdx.x; i < NB; i += 256) hist[i] = 0;
        __syncthreads();
        int beg = b * CHUNK;
        for (int e = beg + threadIdx.x; e < beg + CHUNK; e += 256)
            atomicAdd(&hist[dst[e] >> 7], 1);            // LDS atomic
        __syncthreads();
        for (int i = threadIdx.x; i < NB; i += 256) partialT[i * ABLK + b] = hist[i];
    } else if (b < ABLK + CONV_BLOCKS) {
        int i = (b - ABLK) * 256 + threadIdx.x;          // exact: 800000 elements
        float4 v = ((const float4*)x)[i];
        ((ushort4*)xb)[i] = make_ushort4(f2bf(v.x), f2bf(v.y), f2bf(v.z), f2bf(v.w));
    } else {
        int gid = (b - ABLK - CONV_BLOCKS) * 256 + threadIdx.x;
        if (gid >= 3 * 2048) return;
        int L = gid >> 11, idx = gid & 2047;
        int k = idx >> 5, n = idx & 31;
        const float* Wl = (L == 0) ? Wl1 : (L == 1) ? Wl2 : Wl3;
        const float* Wr = (L == 0) ? Wr1 : (L == 1) ? Wr2 : Wr3;
        float v = (k < 32) ? Wl[k * 32 + n] : Wr[(k - 32) * 32 + n];
        Wcat[gid] = f2bf(v);
    }
}

// ---------------- B1: per-bucket prefix over ABLK chunk-partials (1 wave/bucket) ----------------
__global__ __launch_bounds__(256) void bucket_prefix_kernel(
    const int* __restrict__ partialT, int* __restrict__ baseT, int* __restrict__ tot)
{
    int wave = threadIdx.x >> 6, lane = threadIdx.x & 63;
    int t = blockIdx.x * 4 + wave;
    if (t >= NB) return;
    const int4* p = (const int4*)(partialT + (size_t)t * ABLK);
    int4 u0 = p[lane * 2], u1 = p[lane * 2 + 1];        // 8 partials per lane
    int v0 = u0.x, v1 = u0.y, v2 = u0.z, v3 = u0.w;
    int v4 = u1.x, v5 = u1.y, v6 = u1.z, v7 = u1.w;
    int p0 = 0, p1 = v0, p2 = p1 + v1, p3 = p2 + v2;
    int p4 = p3 + v3, p5 = p4 + v4, p6 = p5 + v5, p7 = p6 + v6;
    int s = p7 + v7;                                     // lane total
    int x = s;                                           // wave inclusive scan
    #pragma unroll
    for (int off = 1; off < 64; off <<= 1) {
        int y = __shfl_up(x, off);
        if (lane >= off) x += y;
    }
    int excl = x - s;                                    // exclusive prefix of lane sums
    int4* q = (int4*)(baseT + (size_t)t * ABLK);
    q[lane * 2]     = make_int4(excl + p0, excl + p1, excl + p2, excl + p3);
    q[lane * 2 + 1] = make_int4(excl + p4, excl + p5, excl + p6, excl + p7);
    if (lane == 63) tot[t] = x;
}

// ---------------- B2: exclusive scan of bucket totals -> bucket starts ----------------
__global__ __launch_bounds__(1024) void total_scan_kernel(
    const int* __restrict__ tot, int* __restrict__ bstart)
{
    __shared__ int tmp[1024];
    int t = threadIdx.x;
    int v = (t < NB) ? tot[t] : 0;
    tmp[t] = v;
    __syncthreads();
    for (int off = 1; off < 1024; off <<= 1) {
        int u = (t >= off) ? tmp[t - off] : 0;
        __syncthreads();
        tmp[t] += u;
        __syncthreads();
    }
    if (t < NB) {
        bstart[t] = tmp[t] - v;
        if (t == NB - 1) bstart[NB] = tmp[t];            // == N_EDGES
    }
}

// ---------------- C: scatter edges into buckets, packed (src | local_node<<17) ----------------
__global__ __launch_bounds__(256) void bucket_scatter_kernel(
    const int* __restrict__ src, const int* __restrict__ dst,
    const int* __restrict__ baseT, const int* __restrict__ bstart,
    int* __restrict__ ebuf)
{
    __shared__ int cur[NB];
    int b = blockIdx.x;
    for (int i = threadIdx.x; i < NB; i += 256)
        cur[i] = bstart[i] + baseT[(size_t)i * ABLK + b];
    __syncthreads();
    int beg = b * CHUNK;
    for (int e = beg + threadIdx.x; e < beg + CHUNK; e += 256) {
        int d = dst[e];
        int slot = atomicAdd(&cur[d >> 7], 1);           // LDS atomic
        ebuf[slot] = src[e] | ((d & 127) << 17);         // src < 2^17
    }
}

// ---------------- D: per-bucket CSR finalize: rowptr, inv, 4-way src-class esrc ----------------
// Each node's neighbor list is stored in 4 src-classes (class = src >> 15,
// ~2MB of bf16 rows each). The aggregate loop walks class 0 edges first
// device-wide, then 1, 2, 3 -> active gather working set always fits L2.
__global__ __launch_bounds__(256) void bucket_csr_kernel(
    const int* __restrict__ bstart, const int* __restrict__ ebuf,
    int* __restrict__ rowptr, float* __restrict__ inv, int* __restrict__ esrc)
{
    __shared__ int hist4[512], cur4[512], tmp[256];
    int b = blockIdx.x;
    int t = threadIdx.x;
    int beg = bstart[b], end = bstart[b + 1];
    hist4[t] = 0; hist4[t + 256] = 0;
    __syncthreads();
    for (int i = beg + t; i < end; i += 256) {
        int p = ebuf[i];
        int ln = (p >> 17) & 127;
        int cls = (p & 0x1FFFF) >> 15;                   // 0..3
        atomicAdd(&hist4[ln * 4 + cls], 1);              // LDS atomic
    }
    __syncthreads();
    int c0 = 0, c1 = 0, c2 = 0, c3 = 0, v = 0;
    if (t < 128) {
        c0 = hist4[t * 4 + 0]; c1 = hist4[t * 4 + 1];
        c2 = hist4[t * 4 + 2]; c3 = hist4[t * 4 + 3];
        v = c0 + c1 + c2 + c3;
    }
    tmp[t] = v;
    __syncthreads();
    for (int off = 1; off < 256; off <<= 1) {
        int u = (t >= off) ? tmp[t - off] : 0;
        __syncthreads();
        tmp[t] += u;
        __syncthreads();
    }
    int excl = tmp[t] - v;                               // exclusive within bucket
    int node = b * 128 + t;
    if (t < 128 && node < N_NODES) {
        int start = beg + excl;
        rowptr[node] = start;
        inv[node] = 1.0f / fmaxf((float)v, 1.0f);
        cur4[t * 4 + 0] = start;
        cur4[t * 4 + 1] = start + c0;
        cur4[t * 4 + 2] = start + c0 + c1;
        cur4[t * 4 + 3] = start + c0 + c1 + c2;
    }
    if (b == NB - 1 && t == 0) rowptr[N_NODES] = N_EDGES;
    __syncthreads();
    for (int i = beg + t; i < end; i += 256) {
        int p = ebuf[i];
        int ln = (p >> 17) & 127;
        int s = p & 0x1FFFF;
        int slot = atomicAdd(&cur4[ln * 4 + (s >> 15)], 1);  // LDS atomic
        esrc[slot] = s;
    }
}

// ---------------- fused layer: aggregate (regs) -> LDS -> MFMA dense -> out ----------------
// Block = 64 nodes. Phase 1: 4 lanes/node, lane owns 8 channels, fp32 acc over
// all neighbors (src-class-ordered -> L2-friendly), 4 neighbors in flight per
// lane; pack bf16 mean into LDS (stride 40 shorts: 16B-aligned, 2-way bank
// aliasing = free). Phase 2: wave w MFMAs nodes [w*16, w*16+16); weights in LDS.
// final=1: layer-3 + 32->8 output projection through a second LDS stage.
__global__ __launch_bounds__(256) void sage_fused_kernel(
    const int* __restrict__ rowptr, const int* __restrict__ esrc,
    const float* __restrict__ inv, const unsigned short* __restrict__ hb,
    const unsigned short* __restrict__ Wcat, const float* __restrict__ bl,
    const float* __restrict__ Wout, const float* __restrict__ bout,
    void* __restrict__ outp, int n_nodes, int final)
{
    __shared__ unsigned short sW[2048];      // 64k x 32n bf16 layer weights
    __shared__ float sb[32];
    __shared__ unsigned short smean[64 * 40];
    __shared__ float sh3[64 * 33];
    __shared__ float sWo[256];
    __shared__ float sbo[8];

    int tid = threadIdx.x;
    ((uint4*)sW)[tid] = ((const uint4*)Wcat)[tid];       // 256 x 16B = 4KB exact
    if (tid < 32) sb[tid] = bl[tid];
    if (final) {
        sWo[tid] = Wout[tid];                            // 256 exact
        if (tid < 8) sbo[tid] = bout[tid];
    }

    int lane = tid & 63, wave = tid >> 6;

    // ---- phase 1: aggregate ----
    int g = lane >> 2, q = lane & 3;
    int nodeA = blockIdx.x * 64 + wave * 16 + g;
    int beg = 0, end = 0;
    if (nodeA < n_nodes) { beg = rowptr[nodeA]; end = rowptr[nodeA + 1]; }
    float a0 = 0.f, a1 = 0.f, a2 = 0.f, a3 = 0.f;
    float a4 = 0.f, a5 = 0.f, a6 = 0.f, a7 = 0.f;
    int j = beg;
    for (; j + 3 < end; j += 4) {
        int s0 = esrc[j];
        int s1 = esrc[j + 1];
        int s2 = esrc[j + 2];
        int s3 = esrc[j + 3];
        uint4 u0 = *(const uint4*)(hb + s0 * 32 + q * 8);
        uint4 u1 = *(const uint4*)(hb + s1 * 32 + q * 8);
        uint4 u2 = *(const uint4*)(hb + s2 * 32 + q * 8);
        uint4 u3 = *(const uint4*)(hb + s3 * 32 + q * 8);
        a0 += bflo(u0.x); a1 += bfhi(u0.x);
        a2 += bflo(u0.y); a3 += bfhi(u0.y);
        a4 += bflo(u0.z); a5 += bfhi(u0.z);
        a6 += bflo(u0.w); a7 += bfhi(u0.w);
        a0 += bflo(u1.x); a1 += bfhi(u1.x);
        a2 += bflo(u1.y); a3 += bfhi(u1.y);
        a4 += bflo(u1.z); a5 += bfhi(u1.z);
        a6 += bflo(u1.w); a7 += bfhi(u1.w);
        a0 += bflo(u2.x); a1 += bfhi(u2.x);
        a2 += bflo(u2.y); a3 += bfhi(u2.y);
        a4 += bflo(u2.z); a5 += bfhi(u2.z);
        a6 += bflo(u2.w); a7 += bfhi(u2.w);
        a0 += bflo(u3.x); a1 += bfhi(u3.x);
        a2 += bflo(u3.y); a3 += bfhi(u3.y);
        a4 += bflo(u3.z); a5 += bfhi(u3.z);
        a6 += bflo(u3.w); a7 += bfhi(u3.w);
    }
    for (; j < end; j++) {
        int s = esrc[j];
        uint4 u = *(const uint4*)(hb + s * 32 + q * 8);
        a0 += bflo(u.x); a1 += bfhi(u.x);
        a2 += bflo(u.y); a3 += bfhi(u.y);
        a4 += bflo(u.z); a5 += bfhi(u.z);
        a6 += bflo(u.w); a7 += bfhi(u.w);
    }
    float iv = (nodeA < n_nodes) ? inv[nodeA] : 0.f;
    uint4 o;
    o.x = (unsigned)f2bf(a0 * iv) | ((unsigned)f2bf(a1 * iv) << 16);
    o.y = (unsigned)f2bf(a2 * iv) | ((unsigned)f2bf(a3 * iv) << 16);
    o.z = (unsigned)f2bf(a4 * iv) | ((unsigned)f2bf(a5 * iv) << 16);
    o.w = (unsigned)f2bf(a6 * iv) | ((unsigned)f2bf(a7 * iv) << 16);
    int mrow = wave * 16 + g;
    *(uint4*)&smean[mrow * 40 + q * 8] = o;
    __syncthreads();

    // ---- phase 2: dense via MFMA ----
    int l15 = lane & 15, quad = lane >> 4;
    s16x8 bf_[2][2];
    #pragma unroll
    for (int kt = 0; kt < 2; kt++)
        #pragma unroll
        for (int nt = 0; nt < 2; nt++)
            #pragma unroll
            for (int jj = 0; jj < 8; jj++) {
                int k = kt * 32 + quad * 8 + jj;
                bf_[kt][nt][jj] = (short)sW[k * 32 + l15 + nt * 16];
            }
    float bias0 = sb[l15], bias1 = sb[l15 + 16];

    int tilebase = blockIdx.x * 64 + wave * 16;
    int nodeD = tilebase + l15;
    int na = min(nodeD, n_nodes - 1);
    s16x8 am = *(const s16x8*)&smean[(wave * 16 + l15) * 40 + quad * 8];
    s16x8 as = *(const s16x8*)(hb + (size_t)na * 32 + quad * 8);
    f32x4 acc0 = {0.f, 0.f, 0.f, 0.f};
    f32x4 acc1 = {0.f, 0.f, 0.f, 0.f};
    acc0 = __builtin_amdgcn_mfma_f32_16x16x32_bf16(am, bf_[0][0], acc0, 0, 0, 0);
    acc0 = __builtin_amdgcn_mfma_f32_16x16x32_bf16(as, bf_[1][0], acc0, 0, 0, 0);
    acc1 = __builtin_amdgcn_mfma_f32_16x16x32_bf16(am, bf_[0][1], acc1, 0, 0, 0);
    acc1 = __builtin_amdgcn_mfma_f32_16x16x32_bf16(as, bf_[1][1], acc1, 0, 0, 0);

    if (!final) {
        #pragma unroll
        for (int r = 0; r < 4; r++) {
            int onode = tilebase + quad * 4 + r;
            if (onode < n_nodes) {
                ((unsigned short*)outp)[onode * 32 + l15]      = f2bf(fmaxf(acc0[r] + bias0, 0.f));
                ((unsigned short*)outp)[onode * 32 + l15 + 16] = f2bf(fmaxf(acc1[r] + bias1, 0.f));
            }
        }
    } else {
        #pragma unroll
        for (int r = 0; r < 4; r++) {
            int row = wave * 16 + quad * 4 + r;
            sh3[row * 33 + l15]      = fmaxf(acc0[r] + bias0, 0.f);
            sh3[row * 33 + l15 + 16] = fmaxf(acc1[r] + bias1, 0.f);
        }
        __syncthreads();
        // 64 nodes x 8 out-channels = 512 outputs, 2 per thread
        #pragma unroll
        for (int i = tid; i < 512; i += 256) {
            int ln = i >> 3, c = i & 7;
            int gn = blockIdx.x * 64 + ln;
            if (gn < N_AGENTS) {
                float ov = sbo[c];
                #pragma unroll
                for (int k = 0; k < 32; k++) ov += sh3[ln * 33 + k] * sWo[k * 8 + c];
                ((float*)outp)[gn * 8 + c] = ov;
            }
        }
    }
}

extern "C" void kernel_launch(void* const* d_in, const int* in_sizes, int n_in,
                              void* d_out, int out_size, void* d_ws, size_t ws_size,
                              hipStream_t stream) {
    const float* x   = (const float*)d_in[0];
    const int* ei    = (const int*)d_in[1];
    const float* Wl1 = (const float*)d_in[2];
    const float* bl1 = (const float*)d_in[3];
    const float* Wr1 = (const float*)d_in[4];
    const float* Wl2 = (const float*)d_in[5];
    const float* bl2 = (const float*)d_in[6];
    const float* Wr2 = (const float*)d_in[7];
    const float* Wl3 = (const float*)d_in[8];
    const float* bl3 = (const float*)d_in[9];
    const float* Wr3 = (const float*)d_in[10];
    const float* Wout = (const float*)d_in[11];
    const float* bout = (const float*)d_in[12];
    float* out = (float*)d_out;

    const int* src = ei;
    const int* dst = ei + N_EDGES;

    // workspace layout (ebuf aliases hAb: ebuf dead after bucket_csr_kernel,
    // hAb first written by fused layer 1)
    char* ws = (char*)d_ws;
    int*   rowptr   = (int*)ws;                                ws += (size_t)(N_NODES + 8) * 4;
    float* inv      = (float*)ws;                              ws += (size_t)N_NODES * 4;
    int*   partialT = (int*)ws;                                ws += (size_t)NB * ABLK * 4;
    int*   baseT    = (int*)ws;                                ws += (size_t)NB * ABLK * 4;
    int*   tot      = (int*)ws;                                ws += 784 * 4;
    int*   bstart   = (int*)ws;                                ws += 784 * 4;
    int*   esrc     = (int*)ws;                                ws += (size_t)N_EDGES * 4;
    unsigned short* hXb   = (unsigned short*)ws;               ws += (size_t)N_NODES * 32 * 2;
    unsigned short* hAb   = (unsigned short*)ws;               ws += (size_t)N_NODES * 32 * 2;
    unsigned short* hBb   = (unsigned short*)ws;               ws += (size_t)N_NODES * 32 * 2;
    unsigned short* Wcat  = (unsigned short*)ws;               ws += 3 * 2048 * 2;
    int*   ebuf     = (int*)hAb;    // alias

    // ---- CSR build (no global atomics) + fused prep ----
    hist_prep_kernel<<<ABLK + CONV_BLOCKS + 24, 256, 0, stream>>>(
        dst, partialT, x, hXb, Wl1, Wr1, Wl2, Wr2, Wl3, Wr3, Wcat);
    bucket_prefix_kernel<<<(NB + 3) / 4, 256, 0, stream>>>(partialT, baseT, tot);
    total_scan_kernel<<<1, 1024, 0, stream>>>(tot, bstart);
    bucket_scatter_kernel<<<ABLK, 256, 0, stream>>>(src, dst, baseT, bstart, ebuf);
    bucket_csr_kernel<<<NB, 256, 0, stream>>>(bstart, ebuf, rowptr, inv, esrc);

    // ---- fused layers ----
    sage_fused_kernel<<<(N_NODES + 63) / 64, 256, 0, stream>>>(
        rowptr, esrc, inv, hXb, Wcat, bl1, Wout, bout, hAb, N_NODES, 0);
    sage_fused_kernel<<<(N_NODES + 63) / 64, 256, 0, stream>>>(
        rowptr, esrc, inv, hAb, Wcat + 2048, bl2, Wout, bout, hBb, N_NODES, 0);
    sage_fused_kernel<<<(N_AGENTS + 63) / 64, 256, 0, stream>>>(
        rowptr, esrc, inv, hBb, Wcat + 4096, bl3, Wout, bout, out, N_AGENTS, 1);
}